// Round 1
// baseline (181.680 us; speedup 1.0000x reference)
//
#include <hip/hip_runtime.h>
#include <hip/hip_bf16.h>
#include <stdint.h>

// ReplicatorDerivLayer: x[8,512,2048] f32, W1/W2 [512,512] f32.
//  F1[f,s] = sum_e x[e,s] W1[e,f]        (per batch)
//  F2[e,s] = sum_f x[f,s] W2[e,f]
//  Wm[s,t] = sum_e F1[e,s] F2[e,t],  zero for t > s (keep lower tri incl diag)
//  fit[e,s] = sum_t Wm[s,t] x[e,t]
//  avg[e]  = sum_s x[e,s] fit[e,s]
//  out     = relu(x * (1 + fit - avg))
//
// All big matmuls in bf16 MFMA (f32 accumulate). Workspace ~129 MB required.

#define SEQ 2048
#define EMB 512
#define NBATCH 8

typedef unsigned short u16;
typedef __bf16 bf16x8 __attribute__((ext_vector_type(8)));
typedef float f32x4 __attribute__((ext_vector_type(4)));

#define AS1 __attribute__((address_space(1)))
#define AS3 __attribute__((address_space(3)))

__device__ __forceinline__ u16 f2bf(float f) {
  // round-to-nearest-even f32 -> bf16 (inputs finite)
  uint32_t u = __builtin_bit_cast(uint32_t, f);
  uint32_t r = u + 0x7FFFu + ((u >> 16) & 1u);
  return (u16)(r >> 16);
}

__device__ __forceinline__ void gld_lds16(const void* g, void* l) {
  __builtin_amdgcn_global_load_lds((AS1 uint32_t*)g, (AS3 uint32_t*)l, 16, 0, 0);
}

// ---------------- cast f32 -> bf16 (vectorized x4) ----------------
__global__ __launch_bounds__(256) void cast_bf16_kernel(const float* __restrict__ in,
                                                        u16* __restrict__ out, int n4) {
  int i = blockIdx.x * 256 + threadIdx.x;
  if (i >= n4) return;
  float4 v = reinterpret_cast<const float4*>(in)[i];
  ushort4 r;
  r.x = f2bf(v.x); r.y = f2bf(v.y); r.z = f2bf(v.z); r.w = f2bf(v.w);
  reinterpret_cast<ushort4*>(out)[i] = r;
}

// ---------------- transpose + cast: in f32 [R][C] -> out bf16 [C][R] ----------------
__global__ __launch_bounds__(256) void transpose_cast_kernel(const float* __restrict__ in,
    u16* __restrict__ out, int R, int C, long sIn, long sOut) {
  __shared__ float tile[32][33];
  const float* ib = in + (size_t)blockIdx.z * sIn;
  u16* ob = out + (size_t)blockIdx.z * sOut;
  const int c0 = blockIdx.x * 32, r0 = blockIdx.y * 32;
  const int tx = threadIdx.x, ty = threadIdx.y;  // (32, 8)
  #pragma unroll
  for (int i = 0; i < 32; i += 8)
    tile[ty + i][tx] = ib[(size_t)(r0 + ty + i) * C + c0 + tx];
  __syncthreads();
  #pragma unroll
  for (int i = 0; i < 32; i += 8)
    ob[(size_t)(c0 + ty + i) * R + r0 + tx] = f2bf(tile[tx][ty + i]);
}

// ---------------- bt-convention GEMM: C[m][n] = sum_k A[m][k]*B[n][k] ----------------
// A: M x K row-major (row stride K), B: N x K row-major (row stride K), bf16.
// OUT_BF16: 1 -> bf16 C, 0 -> f32 C.
// MASKMODE: 0 none; 1 causal (keep n <= m; strictly-upper 128-tiles skipped entirely
//           -- legal because the consumer (MASKMODE==2 pass) never reads them);
//           2 cap K at tn+128 (B rows are zero beyond the diagonal).
template<int OUT_BF16, int MASKMODE>
__global__ __launch_bounds__(256) void gemm_bt_kernel(const u16* __restrict__ A,
    const u16* __restrict__ B, void* __restrict__ Cout,
    int M, int N, int K, long sA, long sB, long sC) {
  const int tid  = threadIdx.x;
  const int lane = tid & 63;
  const int wave = tid >> 6;
  const int tm = blockIdx.y * 128;
  const int tn = blockIdx.x * 128;

  if (MASKMODE == 1 && tn > tm) return;  // strictly-upper tile: never read downstream

  const u16* Ab = A + (size_t)blockIdx.z * sA;
  const u16* Bb = B + (size_t)blockIdx.z * sB;

  __shared__ __align__(16) u16 As[128 * 64];
  __shared__ __align__(16) u16 Bs[128 * 64];

  f32x4 acc[4][4];
  #pragma unroll
  for (int i = 0; i < 4; ++i)
    #pragma unroll
    for (int j = 0; j < 4; ++j) acc[i][j] = (f32x4){0.f, 0.f, 0.f, 0.f};

  const int wm = (wave >> 1) * 64;  // wave's 64x64 sub-tile
  const int wn = (wave & 1) * 64;

  const int Kmax = (MASKMODE == 2) ? ((tn + 128 < K) ? tn + 128 : K) : K;

  for (int k0 = 0; k0 < Kmax; k0 += 64) {
    // stage A tile 128x64 bf16 (16 KB): 4 x (wave writes 1 KB, lane i at base+i*16B)
    #pragma unroll
    for (int it = 0; it < 4; ++it) {
      const int idx = (it * 4 + wave) * 64 + lane;   // 0..1023 chunk index
      const int row = idx >> 3, ch = idx & 7;
      gld_lds16(Ab + (size_t)(tm + row) * K + k0 + ch * 8, As + (it * 4 + wave) * 512);
    }
    #pragma unroll
    for (int it = 0; it < 4; ++it) {
      const int idx = (it * 4 + wave) * 64 + lane;
      const int row = idx >> 3, ch = idx & 7;
      gld_lds16(Bb + (size_t)(tn + row) * K + k0 + ch * 8, Bs + (it * 4 + wave) * 512);
    }
    __syncthreads();

    #pragma unroll
    for (int kk = 0; kk < 2; ++kk) {
      bf16x8 af[4], bfv[4];
      const int col = kk * 32 + (lane >> 4) * 8;
      #pragma unroll
      for (int i = 0; i < 4; ++i)
        af[i] = *reinterpret_cast<const bf16x8*>(As + (wm + i * 16 + (lane & 15)) * 64 + col);
      #pragma unroll
      for (int j = 0; j < 4; ++j)
        bfv[j] = *reinterpret_cast<const bf16x8*>(Bs + (wn + j * 16 + (lane & 15)) * 64 + col);
      #pragma unroll
      for (int i = 0; i < 4; ++i)
        #pragma unroll
        for (int j = 0; j < 4; ++j)
          acc[i][j] = __builtin_amdgcn_mfma_f32_16x16x32_bf16(af[i], bfv[j], acc[i][j], 0, 0, 0);
    }
    __syncthreads();
  }

  // epilogue: D mapping col = lane&15, row = (lane>>4)*4 + r  (measured m89/m91)
  const int r0 = (lane >> 4) * 4;
  const int cn = lane & 15;
  #pragma unroll
  for (int i = 0; i < 4; ++i) {
    #pragma unroll
    for (int j = 0; j < 4; ++j) {
      #pragma unroll
      for (int r = 0; r < 4; ++r) {
        const int m = tm + wm + i * 16 + r0 + r;
        const int n = tn + wn + j * 16 + cn;
        float v = acc[i][j][r];
        if (MASKMODE == 1 && n > m) v = 0.f;
        if (OUT_BF16)
          ((u16*)Cout + (size_t)blockIdx.z * sC)[(size_t)m * N + n] = f2bf(v);
        else
          ((float*)Cout + (size_t)blockIdx.z * sC)[(size_t)m * N + n] = v;
      }
    }
  }
}

// ---------------- finalize: avg-reduce + elementwise + relu ----------------
__global__ __launch_bounds__(256) void finalize_kernel(const float* __restrict__ x,
    const float* __restrict__ fit, float* __restrict__ out) {
  const size_t row = blockIdx.x;  // b*EMB + e
  const float* xr = x + row * SEQ;
  const float* fr = fit + row * SEQ;
  float* orow = out + row * SEQ;
  const int tid = threadIdx.x;

  float4 xv[2], fv[2];
  float part = 0.f;
  #pragma unroll
  for (int i = 0; i < 2; ++i) {
    xv[i] = reinterpret_cast<const float4*>(xr)[i * 256 + tid];
    fv[i] = reinterpret_cast<const float4*>(fr)[i * 256 + tid];
    part += xv[i].x * fv[i].x + xv[i].y * fv[i].y + xv[i].z * fv[i].z + xv[i].w * fv[i].w;
  }
  #pragma unroll
  for (int off = 1; off < 64; off <<= 1) part += __shfl_xor(part, off);
  __shared__ float wsum[4];
  const int wave = tid >> 6, lane = tid & 63;
  if (lane == 0) wsum[wave] = part;
  __syncthreads();
  const float avg = wsum[0] + wsum[1] + wsum[2] + wsum[3];

  #pragma unroll
  for (int i = 0; i < 2; ++i) {
    float4 o;
    o.x = xv[i].x * (1.f + fv[i].x - avg); o.x = o.x > 0.f ? o.x : 0.f;
    o.y = xv[i].y * (1.f + fv[i].y - avg); o.y = o.y > 0.f ? o.y : 0.f;
    o.z = xv[i].z * (1.f + fv[i].z - avg); o.z = o.z > 0.f ? o.z : 0.f;
    o.w = xv[i].w * (1.f + fv[i].w - avg); o.w = o.w > 0.f ? o.w : 0.f;
    reinterpret_cast<float4*>(orow)[i * 256 + tid] = o;
  }
}

extern "C" void kernel_launch(void* const* d_in, const int* in_sizes, int n_in,
                              void* d_out, int out_size, void* d_ws, size_t ws_size,
                              hipStream_t stream) {
  const float* x  = (const float*)d_in[0];
  const float* W1 = (const float*)d_in[1];
  const float* W2 = (const float*)d_in[2];
  float* out = (float*)d_out;

  char* ws = (char*)d_ws;
  const size_t nX = (size_t)NBATCH * EMB * SEQ;  // 8,388,608

  size_t off = 0;
  u16* xb  = (u16*)(ws + off); off += nX * 2;                       // x bf16 [b][e][s]
  u16* xbT = (u16*)(ws + off); off += nX * 2;                       // x bf16 [b][s][e]
  u16* W1t = (u16*)(ws + off); off += (size_t)EMB * EMB * 2;        // W1^T bf16 [f][e]
  u16* W2b = (u16*)(ws + off); off += (size_t)EMB * EMB * 2;        // W2 bf16 [e][f]
  const size_t offF = off;
  u16* F1T = (u16*)(ws + off); off += nX * 2;                       // [b][s][f]
  u16* F2T = (u16*)(ws + off); off += nX * 2;                       // [b][t][e]
  u16* Wm  = (u16*)(ws + off); off += (size_t)NBATCH * SEQ * SEQ * 2; // [b][s][t]
  float* fit = (float*)(ws + offF);  // 32 MB, aliases F1T+F2T (dead after Gram pass)
  // total ws requirement: ~129 MB

  // 1) casts / transposes
  cast_bf16_kernel<<<(int)(nX / 4 / 256), 256, 0, stream>>>(x, xb, (int)(nX / 4));
  cast_bf16_kernel<<<EMB * EMB / 4 / 256, 256, 0, stream>>>(W2, W2b, EMB * EMB / 4);
  transpose_cast_kernel<<<dim3(SEQ / 32, EMB / 32, NBATCH), dim3(32, 8), 0, stream>>>(
      x, xbT, EMB, SEQ, (long)EMB * SEQ, (long)SEQ * EMB);
  transpose_cast_kernel<<<dim3(EMB / 32, EMB / 32, 1), dim3(32, 8), 0, stream>>>(
      W1, W1t, EMB, EMB, 0, 0);

  // 2) projections: F1T[s][f] = sum_e xbT[s][e] W1t[f][e];  F2T[t][e] = sum_f xbT[t][f] W2b[e][f]
  gemm_bt_kernel<1, 0><<<dim3(EMB / 128, SEQ / 128, NBATCH), 256, 0, stream>>>(
      xbT, W1t, F1T, SEQ, EMB, EMB, (long)SEQ * EMB, 0, (long)SEQ * EMB);
  gemm_bt_kernel<1, 0><<<dim3(EMB / 128, SEQ / 128, NBATCH), 256, 0, stream>>>(
      xbT, W2b, F2T, SEQ, EMB, EMB, (long)SEQ * EMB, 0, (long)SEQ * EMB);

  // 3) Gram: Wm[s][t] = sum_f F1T[s][f] F2T[t][f], keep t <= s (upper tiles skipped)
  gemm_bt_kernel<1, 1><<<dim3(SEQ / 128, SEQ / 128, NBATCH), 256, 0, stream>>>(
      F1T, F2T, Wm, SEQ, SEQ, EMB, (long)SEQ * EMB, (long)SEQ * EMB, (long)SEQ * SEQ);

  // 4) fitnesses: fit[e][s] = sum_t xb[e][t] Wm[s][t], K capped at diagonal per n-tile
  gemm_bt_kernel<0, 2><<<dim3(SEQ / 128, EMB / 128, NBATCH), 256, 0, stream>>>(
      xb, Wm, fit, EMB, SEQ, SEQ, (long)EMB * SEQ, (long)SEQ * SEQ, (long)EMB * SEQ);

  // 5) finalize
  finalize_kernel<<<NBATCH * EMB, 256, 0, stream>>>(x, fit, out);
}